// Round 1
// baseline (651.914 us; speedup 1.0000x reference)
//
#include <hip/hip_runtime.h>
#include <cstddef>

// Problem constants
#define NPTS   65536
#define BATCH  4
#define CH     256
#define HWBINS 64     // 8 x 8
#define KDIM   16384  // HWBINS * CH
#define JDIM   512
#define NCHUNK 64     // n-chunks for segment pass (1024 rows each)

// ---------------------------------------------------------------------------
// Bucketization matching np.searchsorted(np.linspace(-1-eps, 1+eps, 9), x, 'right')
// np.linspace is float64: edge_i = i*step + start, edge_8 = stop.
// ---------------------------------------------------------------------------
__device__ __forceinline__ int bucket1d(float xf) {
    const double start = -1.0 - 1e-6;
    const double stop  =  1.0 + 1e-6;
    const double step  = (stop - start) / 8.0;
    double x = (double)xf;
    int k = 0;
#pragma unroll
    for (int i = 0; i < 8; ++i) k += ((double)i * step + start <= x) ? 1 : 0;
    k += (stop <= x) ? 1 : 0;
    int b = k - 1;
    return b < 0 ? 0 : (b > 7 ? 7 : b);
}

// Kernel 1: compute per-point bin + per-block histogram (no global atomics).
// 64 blocks x 256 threads, 4 points/thread.
__global__ __launch_bounds__(256) void k_bins_hist(const float* __restrict__ coords,
                                                   int* __restrict__ bins,
                                                   int* __restrict__ hist) {
    __shared__ int s_h[HWBINS];
    const int tid = threadIdx.x;
    const int blk = blockIdx.x;
    if (tid < HWBINS) s_h[tid] = 0;
    __syncthreads();
#pragma unroll
    for (int i = 0; i < 4; ++i) {
        int n = blk * 1024 + i * 256 + tid;
        float2 xy = *(const float2*)(coords + 2 * (size_t)n);
        int bx = bucket1d(xy.x);
        int by = bucket1d(xy.y);
        int bin = by * 8 + bx;   // (kx-1) + (ky-1)*H, H=8
        bins[n] = bin;
        atomicAdd(&s_h[bin], 1);
    }
    __syncthreads();
    if (tid < HWBINS) hist[blk * HWBINS + tid] = s_h[tid];
}

// ---------------------------------------------------------------------------
// Kernel 2: segment partial sums. The 256 MB pass — must run at HBM speed.
// grid (64 n-chunks, 2 ch-halves, 4 batch) = 512 blocks, 256 thr, 32 KB LDS
// (-> ~5 blocks/CU, 20 waves/CU). Lane = (rowSub 0..7, 32 lanes x float4 =
// 128 channels). LDS accumulate via ds_add_f32 (unsafeAtomicAdd) — handles
// cross-wave same-(bin,ch) RMW races in hardware.
// ---------------------------------------------------------------------------
__global__ __launch_bounds__(256) void k_seg_partial(const float* __restrict__ values,
                                                     const int* __restrict__ bins,
                                                     float* __restrict__ partials) {
    __shared__ float s_sums[HWBINS * 128];   // 32 KB
    const int nc  = blockIdx.x;   // 0..63
    const int chh = blockIdx.y;   // 0..1
    const int b   = blockIdx.z;   // 0..3
    const int tid = threadIdx.x;

    {   // zero LDS
        float4 z = make_float4(0.f, 0.f, 0.f, 0.f);
        float4* s4 = (float4*)s_sums;
        for (int i = tid; i < HWBINS * 128 / 4; i += 256) s4[i] = z;
    }
    __syncthreads();

    const int lane32 = tid & 31;
    const int rsub   = tid >> 5;          // 0..7
    const int n0     = nc * 1024;
    const float* vbase = values + ((size_t)b * NPTS + n0 + rsub) * CH
                                + chh * 128 + lane32 * 4;
    const int* bbase = bins + n0 + rsub;

    for (int i = 0; i < 1024; i += 32) {
        // 4 independent float4 loads in flight (rows i+rsub, +8, +16, +24)
        float4 v0 = *(const float4*)(vbase + (size_t)(i +  0) * CH);
        float4 v1 = *(const float4*)(vbase + (size_t)(i +  8) * CH);
        float4 v2 = *(const float4*)(vbase + (size_t)(i + 16) * CH);
        float4 v3 = *(const float4*)(vbase + (size_t)(i + 24) * CH);
        int b0 = bbase[i];
        int b1 = bbase[i + 8];
        int b2 = bbase[i + 16];
        int b3 = bbase[i + 24];
        float* p0 = &s_sums[b0 * 128 + lane32 * 4];
        float* p1 = &s_sums[b1 * 128 + lane32 * 4];
        float* p2 = &s_sums[b2 * 128 + lane32 * 4];
        float* p3 = &s_sums[b3 * 128 + lane32 * 4];
        unsafeAtomicAdd(p0 + 0, v0.x); unsafeAtomicAdd(p0 + 1, v0.y);
        unsafeAtomicAdd(p0 + 2, v0.z); unsafeAtomicAdd(p0 + 3, v0.w);
        unsafeAtomicAdd(p1 + 0, v1.x); unsafeAtomicAdd(p1 + 1, v1.y);
        unsafeAtomicAdd(p1 + 2, v1.z); unsafeAtomicAdd(p1 + 3, v1.w);
        unsafeAtomicAdd(p2 + 0, v2.x); unsafeAtomicAdd(p2 + 1, v2.y);
        unsafeAtomicAdd(p2 + 2, v2.z); unsafeAtomicAdd(p2 + 3, v2.w);
        unsafeAtomicAdd(p3 + 0, v3.x); unsafeAtomicAdd(p3 + 1, v3.y);
        unsafeAtomicAdd(p3 + 2, v3.z); unsafeAtomicAdd(p3 + 3, v3.w);
    }
    __syncthreads();

    // flush 8192 floats (32 KB) to global partials, coalesced float4
    float* dst = partials + ((size_t)((b * NCHUNK + nc) * 2 + chh)) * 8192;
    const float4* s4 = (const float4*)s_sums;
    float4* d4 = (float4*)dst;
    for (int i = tid; i < 2048; i += 256) d4[i] = s4[i];
}

// ---------------------------------------------------------------------------
// Kernel 3: reduce partials -> means[b][bin*256+c] (divide by max(count,1)).
// grid (64 bins, 4 b), 256 threads (c). Reads 16 MB coalesced.
// ---------------------------------------------------------------------------
__global__ __launch_bounds__(256) void k_means(const float* __restrict__ partials,
                                               const int* __restrict__ hist,
                                               float* __restrict__ means) {
    const int bin = blockIdx.x;
    const int b   = blockIdx.y;
    const int tid = threadIdx.x;

    int cnt = 0;
#pragma unroll 8
    for (int t = 0; t < 64; ++t) cnt += hist[t * HWBINS + bin];
    const float denom = fmaxf((float)cnt, 1.0f);

    const int chh = tid >> 7;        // 0..1
    const int cp  = tid & 127;
    float s = 0.f;
#pragma unroll 8
    for (int nc = 0; nc < NCHUNK; ++nc) {
        s += partials[((size_t)((b * NCHUNK + nc) * 2 + chh)) * 8192
                      + (size_t)bin * 128 + cp];
    }
    means[(size_t)b * KDIM + bin * CH + tid] = s / denom;
}

// ---------------------------------------------------------------------------
// Kernel 4: GEMM stage A — partial dot over k-chunks.
// grid (2 j-halves, 128 k-chunks of 128), 256 threads. Reads W (32 MB) once.
// ---------------------------------------------------------------------------
__global__ __launch_bounds__(256) void k_gemm_a(const float* __restrict__ Wm,
                                                const float* __restrict__ means,
                                                float* __restrict__ p4) {
    __shared__ float s_m[4 * 128];
    const int jb  = blockIdx.x;   // 0..1
    const int kc  = blockIdx.y;   // 0..127
    const int tid = threadIdx.x;
    const int k0  = kc * 128;

    for (int i = tid; i < 512; i += 256) {
        int bb = i >> 7, kk = i & 127;
        s_m[i] = means[(size_t)bb * KDIM + k0 + kk];
    }
    __syncthreads();

    const int j = jb * 256 + tid;
    float a0 = 0.f, a1 = 0.f, a2 = 0.f, a3 = 0.f;
#pragma unroll 4
    for (int kk = 0; kk < 128; ++kk) {
        float w = Wm[(size_t)(k0 + kk) * JDIM + j];
        a0 += s_m[kk] * w;
        a1 += s_m[128 + kk] * w;
        a2 += s_m[256 + kk] * w;
        a3 += s_m[384 + kk] * w;
    }
    p4[((size_t)kc * 4 + 0) * JDIM + j] = a0;
    p4[((size_t)kc * 4 + 1) * JDIM + j] = a1;
    p4[((size_t)kc * 4 + 2) * JDIM + j] = a2;
    p4[((size_t)kc * 4 + 3) * JDIM + j] = a3;
}

// Kernel 5: GEMM stage B — reduce 128 k-chunk partials + bias.
__global__ __launch_bounds__(256) void k_gemm_b(const float* __restrict__ p4,
                                                const float* __restrict__ bias,
                                                float* __restrict__ out) {
    const int idx = blockIdx.x * 256 + threadIdx.x;   // 0..2047
    const int b = idx >> 9;
    const int j = idx & 511;
    float s = bias[j];
#pragma unroll 8
    for (int kc = 0; kc < 128; ++kc) s += p4[((size_t)kc * 4 + b) * JDIM + j];
    out[idx] = s;
}

// ---------------------------------------------------------------------------
extern "C" void kernel_launch(void* const* d_in, const int* in_sizes, int n_in,
                              void* d_out, int out_size, void* d_ws, size_t ws_size,
                              hipStream_t stream) {
    const float* values = (const float*)d_in[0];  // [4, 65536, 256]
    const float* coords = (const float*)d_in[1];  // [65536, 2]
    const float* Wm     = (const float*)d_in[2];  // [16384, 512]
    const float* bias   = (const float*)d_in[3];  // [512]
    float* out = (float*)d_out;                   // [4, 512]

    char* ws = (char*)d_ws;
    // ws layout (bytes):
    //   bins:     0            .. 262144      (65536 int)
    //   hist:     262144       .. 278528      (64*64 int)
    //   partials: 278528       .. 17056  K    (512 blocks * 8192 f = 16 MB)
    //   means:    +16777216                   (4*16384 f = 256 KB)
    //   p4:       +262144                     (128*4*512 f = 1 MB)
    int*   bins     = (int*)ws;
    int*   hist     = (int*)(ws + 262144);
    float* partials = (float*)(ws + 278528);
    float* means    = (float*)(ws + 278528 + 16777216);
    float* p4       = (float*)(ws + 278528 + 16777216 + 262144);

    k_bins_hist<<<64, 256, 0, stream>>>(coords, bins, hist);
    k_seg_partial<<<dim3(NCHUNK, 2, BATCH), 256, 0, stream>>>(values, bins, partials);
    k_means<<<dim3(HWBINS, BATCH), 256, 0, stream>>>(partials, hist, means);
    k_gemm_a<<<dim3(2, 128), 256, 0, stream>>>(Wm, means, p4);
    k_gemm_b<<<8, 256, 0, stream>>>(p4, bias, out);
}

// Round 2
// 411.341 us; speedup vs baseline: 1.5849x; 1.5849x over previous
//
#include <hip/hip_runtime.h>
#include <cstddef>

// Problem constants
#define NPTS   65536
#define BATCH  4
#define CH     256
#define HWBINS 64     // 8 x 8
#define KDIM   16384  // HWBINS * CH
#define JDIM   512
#define CHUNK  32     // rows per block in the big segment pass -> 2048 blocks

// ---------------------------------------------------------------------------
// Bucketization matching np.searchsorted(np.linspace(-1-eps, 1+eps, 9), x,
// 'right'). np.linspace is float64. (Verified correct in R0: absmax 6e-5.)
// ---------------------------------------------------------------------------
__device__ __forceinline__ int bucket1d(float xf) {
    const double start = -1.0 - 1e-6;
    const double stop  =  1.0 + 1e-6;
    const double step  = (stop - start) / 8.0;
    double x = (double)xf;
    int k = 0;
#pragma unroll
    for (int i = 0; i < 8; ++i) k += ((double)i * step + start <= x) ? 1 : 0;
    k += (stop <= x) ? 1 : 0;
    int b = k - 1;
    return b < 0 ? 0 : (b > 7 ? 7 : b);
}

// Zero sums[65536] and out_part[16384] (ws is poisoned 0xAA before each call).
__global__ __launch_bounds__(256) void k_zero(float4* __restrict__ sums4,
                                              float4* __restrict__ part4) {
    const int idx = blockIdx.x * 256 + threadIdx.x;   // grid 80*256 = 20480
    const float4 z = make_float4(0.f, 0.f, 0.f, 0.f);
    if (idx < 16384) sums4[idx] = z;
    else             part4[idx - 16384] = z;          // 4096 float4
}

// Kernel 1: per-point bin + per-block histogram (no global atomics).
__global__ __launch_bounds__(256) void k_bins(const float* __restrict__ coords,
                                              int* __restrict__ bins,
                                              int* __restrict__ hist_blk) {
    __shared__ int s_h[HWBINS];
    const int tid = threadIdx.x;
    const int blk = blockIdx.x;
    if (tid < HWBINS) s_h[tid] = 0;
    __syncthreads();
#pragma unroll
    for (int i = 0; i < 4; ++i) {
        int n = blk * 1024 + i * 256 + tid;
        float2 xy = *(const float2*)(coords + 2 * (size_t)n);
        int bx = bucket1d(xy.x);
        int by = bucket1d(xy.y);
        int bin = by * 8 + bx;   // (kx-1) + (ky-1)*H, H=8
        bins[n] = bin;
        atomicAdd(&s_h[bin], 1);
    }
    __syncthreads();
    if (tid < HWBINS) hist_blk[blk * HWBINS + tid] = s_h[tid];
}

// Kernel 2: one wave. counts[bin], exclusive bin offsets, per-block bases.
__global__ void k_scan(const int* __restrict__ hist_blk,
                       int* __restrict__ counts,
                       int* __restrict__ block_base) {
    const int b = threadIdx.x;   // 0..63
    int tot = 0;
#pragma unroll 8
    for (int blk = 0; blk < 64; ++blk) tot += hist_blk[blk * HWBINS + b];
    counts[b] = tot;
    // inclusive scan across the 64 lanes
    int inc = tot;
#pragma unroll
    for (int d = 1; d < 64; d <<= 1) {
        int v = __shfl_up(inc, d, 64);
        if (b >= d) inc += v;
    }
    int run = inc - tot;   // exclusive offset of this bin
#pragma unroll 8
    for (int blk = 0; blk < 64; ++blk) {
        int h = hist_blk[blk * HWBINS + b];
        block_base[blk * HWBINS + b] = run;
        run += h;
    }
}

// Kernel 3: scatter (row, bin) pairs into bin-sorted order.
__global__ __launch_bounds__(256) void k_scatter(const int* __restrict__ bins,
                                                 const int* __restrict__ block_base,
                                                 int2* __restrict__ pairs) {
    __shared__ int s_cur[HWBINS];
    const int tid = threadIdx.x;
    const int blk = blockIdx.x;
    if (tid < HWBINS) s_cur[tid] = block_base[blk * HWBINS + tid];
    __syncthreads();
#pragma unroll
    for (int i = 0; i < 4; ++i) {
        int n = blk * 1024 + i * 256 + tid;
        int bin = bins[n];
        int pos = atomicAdd(&s_cur[bin], 1);
        pairs[pos] = make_int2(n, bin);
    }
}

// ---------------------------------------------------------------------------
// Kernel 4: the 256 MB pass. 2048 blocks (8/CU), 256 thr = 4 waves = 4
// batches. Wave: 64 lanes x float4 = all 256 channels of one row. Rows are
// bin-sorted -> register accumulate, flush (global_atomic_add_f32) only on
// bin change. 4-deep manual prefetch keeps ~64 KB/CU of loads in flight.
// ---------------------------------------------------------------------------
__global__ __launch_bounds__(256) void k_seg(const float* __restrict__ values,
                                             const int2* __restrict__ pairs,
                                             float* __restrict__ sums) {
    __shared__ int2 sp[CHUNK];
    const int tid = threadIdx.x;
    const int r0  = blockIdx.x * CHUNK;
    if (tid < CHUNK) sp[tid] = pairs[r0 + tid];
    __syncthreads();

    const int w    = tid >> 6;    // batch
    const int lane = tid & 63;    // channel group (float4)
    const float* vb = values + (size_t)w * NPTS * CH + lane * 4;
    float* sb = sums + (size_t)w * HWBINS * CH + lane * 4;

    float4 acc = make_float4(0.f, 0.f, 0.f, 0.f);
    int cur = sp[0].y;

    auto flushfn = [&](int nb) {
        float* d = sb + (size_t)cur * CH;
        unsafeAtomicAdd(d + 0, acc.x);
        unsafeAtomicAdd(d + 1, acc.y);
        unsafeAtomicAdd(d + 2, acc.z);
        unsafeAtomicAdd(d + 3, acc.w);
        acc = make_float4(0.f, 0.f, 0.f, 0.f);
        cur = nb;
    };

    float4 a0 = *(const float4*)(vb + (size_t)sp[0].x * CH);
    float4 a1 = *(const float4*)(vb + (size_t)sp[1].x * CH);
    float4 a2 = *(const float4*)(vb + (size_t)sp[2].x * CH);
    float4 a3 = *(const float4*)(vb + (size_t)sp[3].x * CH);

#pragma unroll
    for (int g = 0; g < CHUNK; g += 4) {
        float4 n0, n1, n2, n3;
        if (g + 4 < CHUNK) {           // issue next group's loads first
            n0 = *(const float4*)(vb + (size_t)sp[g + 4].x * CH);
            n1 = *(const float4*)(vb + (size_t)sp[g + 5].x * CH);
            n2 = *(const float4*)(vb + (size_t)sp[g + 6].x * CH);
            n3 = *(const float4*)(vb + (size_t)sp[g + 7].x * CH);
        }
        int b0 = sp[g].y, b1 = sp[g + 1].y, b2 = sp[g + 2].y, b3 = sp[g + 3].y;
        if (b0 != cur) flushfn(b0);    // wave-uniform branches, rare
        acc.x += a0.x; acc.y += a0.y; acc.z += a0.z; acc.w += a0.w;
        if (b1 != cur) flushfn(b1);
        acc.x += a1.x; acc.y += a1.y; acc.z += a1.z; acc.w += a1.w;
        if (b2 != cur) flushfn(b2);
        acc.x += a2.x; acc.y += a2.y; acc.z += a2.z; acc.w += a2.w;
        if (b3 != cur) flushfn(b3);
        acc.x += a3.x; acc.y += a3.y; acc.z += a3.z; acc.w += a3.w;
        if (g + 4 < CHUNK) { a0 = n0; a1 = n1; a2 = n2; a3 = n3; }
    }
    flushfn(cur);   // final flush
}

// ---------------------------------------------------------------------------
// Kernel 5: GEMM partials. 512 blocks (k-chunks of 32), 256 thr, each thread
// owns a float2 of j. Mean division folded into the LDS stage. Full unroll
// -> 32 independent loads in flight. Accumulate into 8 slots to avoid
// same-address atomic hotspots.
// ---------------------------------------------------------------------------
__global__ __launch_bounds__(256) void k_gemm_a(const float* __restrict__ Wm,
                                                const float* __restrict__ sums,
                                                const int* __restrict__ counts,
                                                float* __restrict__ out_part) {
    __shared__ float s_m[4 * 32];   // [batch][kk]
    const int tid = threadIdx.x;
    const int kc  = blockIdx.x;     // 0..511
    const int k0  = kc * 32;
    if (tid < 128) {
        int bb = tid >> 5, kk = tid & 31, k = k0 + kk;
        float cnt = (float)counts[k >> 8];
        s_m[tid] = sums[(size_t)bb * KDIM + k] / fmaxf(cnt, 1.0f);
    }
    __syncthreads();

    const float2* W2 = (const float2*)Wm;
    const float2* wp = W2 + (size_t)k0 * 256 + tid;
    float2 a0 = {0.f, 0.f}, a1 = {0.f, 0.f}, a2 = {0.f, 0.f}, a3 = {0.f, 0.f};
#pragma unroll
    for (int kk = 0; kk < 32; ++kk) {
        float2 w = wp[(size_t)kk * 256];
        float m0 = s_m[kk], m1 = s_m[32 + kk], m2 = s_m[64 + kk], m3 = s_m[96 + kk];
        a0.x += m0 * w.x; a0.y += m0 * w.y;
        a1.x += m1 * w.x; a1.y += m1 * w.y;
        a2.x += m2 * w.x; a2.y += m2 * w.y;
        a3.x += m3 * w.x; a3.y += m3 * w.y;
    }
    const int slot = kc & 7;
    float* op = out_part + (size_t)slot * 2048 + 2 * tid;
    unsafeAtomicAdd(op + 0,    a0.x); unsafeAtomicAdd(op + 1,    a0.y);
    unsafeAtomicAdd(op + 512,  a1.x); unsafeAtomicAdd(op + 513,  a1.y);
    unsafeAtomicAdd(op + 1024, a2.x); unsafeAtomicAdd(op + 1025, a2.y);
    unsafeAtomicAdd(op + 1536, a3.x); unsafeAtomicAdd(op + 1537, a3.y);
}

// Kernel 6: reduce 8 slots + bias -> out[4][512].
__global__ __launch_bounds__(256) void k_gemm_b(const float* __restrict__ out_part,
                                                const float* __restrict__ bias,
                                                float* __restrict__ out) {
    const int idx = blockIdx.x * 256 + threadIdx.x;   // 0..2047
    const int j = idx & 511;
    float s = bias[j];
#pragma unroll
    for (int sl = 0; sl < 8; ++sl) s += out_part[(size_t)sl * 2048 + idx];
    out[idx] = s;
}

// ---------------------------------------------------------------------------
extern "C" void kernel_launch(void* const* d_in, const int* in_sizes, int n_in,
                              void* d_out, int out_size, void* d_ws, size_t ws_size,
                              hipStream_t stream) {
    const float* values = (const float*)d_in[0];  // [4, 65536, 256]
    const float* coords = (const float*)d_in[1];  // [65536, 2]
    const float* Wm     = (const float*)d_in[2];  // [16384, 512]
    const float* bias   = (const float*)d_in[3];  // [512]
    float* out = (float*)d_out;                   // [4, 512]

    char* ws = (char*)d_ws;
    // ws layout (bytes):
    int*   bins       = (int*)(ws + 0);            //  256 KB
    int*   hist_blk   = (int*)(ws + 262144);       //   16 KB
    int*   counts     = (int*)(ws + 278528);       //  256 B
    int*   block_base = (int*)(ws + 278784);       //   16 KB
    int2*  pairs      = (int2*)(ws + 295168);      //  512 KB
    float* sums       = (float*)(ws + 819456);     //  256 KB  [4][64][256]
    float* out_part   = (float*)(ws + 1081600);    //   64 KB  [8][2048]

    k_zero   <<<80, 256, 0, stream>>>((float4*)sums, (float4*)out_part);
    k_bins   <<<64, 256, 0, stream>>>(coords, bins, hist_blk);
    k_scan   <<<1, 64, 0, stream>>>(hist_blk, counts, block_base);
    k_scatter<<<64, 256, 0, stream>>>(bins, block_base, pairs);
    k_seg    <<<NPTS / CHUNK, 256, 0, stream>>>(values, pairs, sums);
    k_gemm_a <<<512, 256, 0, stream>>>(Wm, sums, counts, out_part);
    k_gemm_b <<<8, 256, 0, stream>>>(out_part, bias, out);
}

// Round 3
// 396.779 us; speedup vs baseline: 1.6430x; 1.0367x over previous
//
#include <hip/hip_runtime.h>
#include <cstddef>

// Problem constants
#define NPTS   65536
#define BATCH  4
#define CH     256
#define HWBINS 64     // 8 x 8
#define KDIM   16384  // HWBINS * CH
#define JDIM   512
#define CHUNK  64     // rows per block in the big segment pass -> 1024 blocks
#define SSLOTS 8      // slot-spread copies of sums (atomic contention killer)
#define GSLOTS 32     // slot-spread copies of gemm partials

// ---------------------------------------------------------------------------
// Bucketization matching np.searchsorted(np.linspace(-1-eps, 1+eps, 9), x,
// 'right'). np.linspace is float64. (Verified: absmax 6e-5 in R1/R2.)
// ---------------------------------------------------------------------------
__device__ __forceinline__ int bucket1d(float xf) {
    const double start = -1.0 - 1e-6;
    const double stop  =  1.0 + 1e-6;
    const double step  = (stop - start) / 8.0;
    double x = (double)xf;
    int k = 0;
#pragma unroll
    for (int i = 0; i < 8; ++i) k += ((double)i * step + start <= x) ? 1 : 0;
    k += (stop <= x) ? 1 : 0;
    int b = k - 1;
    return b < 0 ? 0 : (b > 7 ? 7 : b);
}

// Kernel 1: zero sums8+out_part (contiguous 2.25 MB) + per-point bin +
// per-block histogram. 64 blocks x 256 threads.
__global__ __launch_bounds__(256) void k_bins(const float* __restrict__ coords,
                                              int* __restrict__ bins,
                                              int* __restrict__ hist_blk,
                                              float4* __restrict__ zero4) {
    __shared__ int s_h[HWBINS];
    const int tid = threadIdx.x;
    const int blk = blockIdx.x;
    // zero 2.25 MB = 147456 float4 across 16384 threads (9 each), coalesced
    {
        const float4 z = make_float4(0.f, 0.f, 0.f, 0.f);
        for (int i = blk * 256 + tid; i < (SSLOTS * BATCH * KDIM + GSLOTS * 2048) / 4;
             i += 64 * 256)
            zero4[i] = z;
    }
    if (tid < HWBINS) s_h[tid] = 0;
    __syncthreads();
#pragma unroll
    for (int i = 0; i < 4; ++i) {
        int n = blk * 1024 + i * 256 + tid;
        float2 xy = *(const float2*)(coords + 2 * (size_t)n);
        int bx = bucket1d(xy.x);
        int by = bucket1d(xy.y);
        int bin = by * 8 + bx;   // (kx-1) + (ky-1)*H, H=8
        bins[n] = bin;
        atomicAdd(&s_h[bin], 1);
    }
    __syncthreads();
    if (tid < HWBINS) hist_blk[blk * HWBINS + tid] = s_h[tid];
}

// Kernel 2: one wave. counts[bin], exclusive bin offsets, per-block bases.
__global__ void k_scan(const int* __restrict__ hist_blk,
                       int* __restrict__ counts,
                       int* __restrict__ block_base) {
    const int b = threadIdx.x;   // 0..63
    int tot = 0;
#pragma unroll 8
    for (int blk = 0; blk < 64; ++blk) tot += hist_blk[blk * HWBINS + b];
    counts[b] = tot;
    int inc = tot;
#pragma unroll
    for (int d = 1; d < 64; d <<= 1) {
        int v = __shfl_up(inc, d, 64);
        if (b >= d) inc += v;
    }
    int run = inc - tot;   // exclusive offset of this bin
#pragma unroll 8
    for (int blk = 0; blk < 64; ++blk) {
        int h = hist_blk[blk * HWBINS + b];
        block_base[blk * HWBINS + b] = run;
        run += h;
    }
}

// Kernel 3: scatter (row, bin) pairs into bin-sorted order.
__global__ __launch_bounds__(256) void k_scatter(const int* __restrict__ bins,
                                                 const int* __restrict__ block_base,
                                                 int2* __restrict__ pairs) {
    __shared__ int s_cur[HWBINS];
    const int tid = threadIdx.x;
    const int blk = blockIdx.x;
    if (tid < HWBINS) s_cur[tid] = block_base[blk * HWBINS + tid];
    __syncthreads();
#pragma unroll
    for (int i = 0; i < 4; ++i) {
        int n = blk * 1024 + i * 256 + tid;
        int bin = bins[n];
        int pos = atomicAdd(&s_cur[bin], 1);
        pairs[pos] = make_int2(n, bin);
    }
}

// ---------------------------------------------------------------------------
// Kernel 4: the 256 MB pass. 1024 blocks (4/CU, 16 waves/CU -> ~64 KB loads
// in flight per CU vs ~9 KB needed at 6.3 TB/s). Wave = one batch, 64 lanes x
// float4 = all 256 ch of a row. Rows bin-sorted -> register accumulate; flush
// via global f32 atomics only at bin boundaries, spread over 8 sum slots
// (contention ~2 per address).
// ---------------------------------------------------------------------------
__global__ __launch_bounds__(256) void k_seg(const float* __restrict__ values,
                                             const int2* __restrict__ pairs,
                                             float* __restrict__ sums8) {
    __shared__ int2 sp[CHUNK];
    const int tid = threadIdx.x;
    const int r0  = blockIdx.x * CHUNK;
    if (tid < CHUNK) sp[tid] = pairs[r0 + tid];
    __syncthreads();

    const int w    = tid >> 6;    // batch
    const int lane = tid & 63;    // channel group (float4)
    const int slot = blockIdx.x & (SSLOTS - 1);
    const float* vb = values + (size_t)w * NPTS * CH + lane * 4;
    float* sb = sums8 + (size_t)slot * BATCH * KDIM + (size_t)w * KDIM + lane * 4;

    float4 acc = make_float4(0.f, 0.f, 0.f, 0.f);
    int cur = sp[0].y;

    auto flushfn = [&](int nb) {
        float* d = sb + (size_t)cur * CH;
        unsafeAtomicAdd(d + 0, acc.x);
        unsafeAtomicAdd(d + 1, acc.y);
        unsafeAtomicAdd(d + 2, acc.z);
        unsafeAtomicAdd(d + 3, acc.w);
        acc = make_float4(0.f, 0.f, 0.f, 0.f);
        cur = nb;
    };

    float4 a0 = *(const float4*)(vb + (size_t)sp[0].x * CH);
    float4 a1 = *(const float4*)(vb + (size_t)sp[1].x * CH);
    float4 a2 = *(const float4*)(vb + (size_t)sp[2].x * CH);
    float4 a3 = *(const float4*)(vb + (size_t)sp[3].x * CH);

#pragma unroll
    for (int g = 0; g < CHUNK; g += 4) {
        float4 n0, n1, n2, n3;
        if (g + 4 < CHUNK) {           // issue next group's loads first
            n0 = *(const float4*)(vb + (size_t)sp[g + 4].x * CH);
            n1 = *(const float4*)(vb + (size_t)sp[g + 5].x * CH);
            n2 = *(const float4*)(vb + (size_t)sp[g + 6].x * CH);
            n3 = *(const float4*)(vb + (size_t)sp[g + 7].x * CH);
        }
        int b0 = sp[g].y, b1 = sp[g + 1].y, b2 = sp[g + 2].y, b3 = sp[g + 3].y;
        if (b0 != cur) flushfn(b0);    // wave-uniform branches, rare
        acc.x += a0.x; acc.y += a0.y; acc.z += a0.z; acc.w += a0.w;
        if (b1 != cur) flushfn(b1);
        acc.x += a1.x; acc.y += a1.y; acc.z += a1.z; acc.w += a1.w;
        if (b2 != cur) flushfn(b2);
        acc.x += a2.x; acc.y += a2.y; acc.z += a2.z; acc.w += a2.w;
        if (b3 != cur) flushfn(b3);
        acc.x += a3.x; acc.y += a3.y; acc.z += a3.z; acc.w += a3.w;
        if (g + 4 < CHUNK) { a0 = n0; a1 = n1; a2 = n2; a3 = n3; }
    }
    flushfn(cur);   // final flush
}

// ---------------------------------------------------------------------------
// Kernel 5: GEMM partials. 256 blocks (k-chunks of 64), 256 thr, each thread
// owns a float2 of j for all 4 batches. Means (8-slot sum / count) computed
// into LDS. 64 fully-unrolled row loads in flight. Partials into 32 slots
// (8-way atomic contention, spread over time).
// ---------------------------------------------------------------------------
__global__ __launch_bounds__(256) void k_gemm_a(const float* __restrict__ Wm,
                                                const float* __restrict__ sums8,
                                                const int* __restrict__ counts,
                                                float* __restrict__ out_part) {
    __shared__ float s_m[4 * 64];   // [batch][kk]
    const int tid = threadIdx.x;
    const int kc  = blockIdx.x;     // 0..255
    const int k0  = kc * 64;
    {
        int bb = tid >> 6, kk = tid & 63, k = k0 + kk;
        float s = 0.f;
#pragma unroll
        for (int sl = 0; sl < SSLOTS; ++sl)
            s += sums8[(size_t)sl * BATCH * KDIM + (size_t)bb * KDIM + k];
        float cnt = (float)counts[k >> 8];
        s_m[tid] = s / fmaxf(cnt, 1.0f);
    }
    __syncthreads();

    const float2* W2 = (const float2*)Wm;
    const float2* wp = W2 + (size_t)k0 * 256 + tid;
    float2 a0 = {0.f, 0.f}, a1 = {0.f, 0.f}, a2 = {0.f, 0.f}, a3 = {0.f, 0.f};
#pragma unroll
    for (int kk = 0; kk < 64; ++kk) {
        float2 w = wp[(size_t)kk * 256];
        float m0 = s_m[kk], m1 = s_m[64 + kk], m2 = s_m[128 + kk], m3 = s_m[192 + kk];
        a0.x += m0 * w.x; a0.y += m0 * w.y;
        a1.x += m1 * w.x; a1.y += m1 * w.y;
        a2.x += m2 * w.x; a2.y += m2 * w.y;
        a3.x += m3 * w.x; a3.y += m3 * w.y;
    }
    const int slot = kc & (GSLOTS - 1);
    float* op = out_part + (size_t)slot * 2048 + 2 * tid;
    unsafeAtomicAdd(op + 0,    a0.x); unsafeAtomicAdd(op + 1,    a0.y);
    unsafeAtomicAdd(op + 512,  a1.x); unsafeAtomicAdd(op + 513,  a1.y);
    unsafeAtomicAdd(op + 1024, a2.x); unsafeAtomicAdd(op + 1025, a2.y);
    unsafeAtomicAdd(op + 1536, a3.x); unsafeAtomicAdd(op + 1537, a3.y);
}

// Kernel 6: reduce 32 slots + bias -> out[4][512]. 256 KB read by 8 blocks.
__global__ __launch_bounds__(256) void k_gemm_b(const float* __restrict__ out_part,
                                                const float* __restrict__ bias,
                                                float* __restrict__ out) {
    const int idx = blockIdx.x * 256 + threadIdx.x;   // 0..2047
    const int j = idx & 511;
    float s = bias[j];
#pragma unroll
    for (int sl = 0; sl < GSLOTS; ++sl) s += out_part[(size_t)sl * 2048 + idx];
    out[idx] = s;
}

// ---------------------------------------------------------------------------
extern "C" void kernel_launch(void* const* d_in, const int* in_sizes, int n_in,
                              void* d_out, int out_size, void* d_ws, size_t ws_size,
                              hipStream_t stream) {
    const float* values = (const float*)d_in[0];  // [4, 65536, 256]
    const float* coords = (const float*)d_in[1];  // [65536, 2]
    const float* Wm     = (const float*)d_in[2];  // [16384, 512]
    const float* bias   = (const float*)d_in[3];  // [512]
    float* out = (float*)d_out;                   // [4, 512]

    char* ws = (char*)d_ws;
    // ws layout (bytes):
    int*   bins       = (int*)(ws + 0);            //  256 KB
    int*   hist_blk   = (int*)(ws + 262144);       //   16 KB
    int*   counts     = (int*)(ws + 278528);       //  256 B
    int*   block_base = (int*)(ws + 278784);       //   16 KB
    int2*  pairs      = (int2*)(ws + 295168);      //  512 KB
    float* sums8      = (float*)(ws + 819456);     //    2 MB  [8][4][16384]
    float* out_part   = (float*)(ws + 2916608);    //  256 KB  [32][2048] (MUST follow sums8: zeroed as one range)

    k_bins   <<<64, 256, 0, stream>>>(coords, bins, hist_blk, (float4*)sums8);
    k_scan   <<<1, 64, 0, stream>>>(hist_blk, counts, block_base);
    k_scatter<<<64, 256, 0, stream>>>(bins, block_base, pairs);
    k_seg    <<<NPTS / CHUNK, 256, 0, stream>>>(values, pairs, sums8);
    k_gemm_a <<<256, 256, 0, stream>>>(Wm, sums8, counts, out_part);
    k_gemm_b <<<8, 256, 0, stream>>>(out_part, bias, out);
}

// Round 5
// 391.668 us; speedup vs baseline: 1.6645x; 1.0130x over previous
//
#include <hip/hip_runtime.h>
#include <cstddef>

// Problem constants
#define NPTS   65536
#define BATCH  4
#define CH     256
#define HWBINS 64     // 8 x 8
#define KDIM   16384  // HWBINS * CH
#define JDIM   512
#define CHUNK  64     // rows per block in the big segment pass -> 1024 blocks
#define SSLOTS 8      // slot-spread copies of sums (atomic contention killer)
#define GSLOTS 64     // slot-spread copies of gemm partials
#define ZERO_F4 ((SSLOTS * BATCH * KDIM + GSLOTS * 2048) / 4)   // 163840 float4

// Native clang vector types — __builtin_nontemporal_load requires these
// (HIP_vector_type float4/float2 are structs and are rejected).
typedef float vf4 __attribute__((ext_vector_type(4)));
typedef float vf2 __attribute__((ext_vector_type(2)));

__device__ __forceinline__ float4 ntload4(const float* p) {
    vf4 v = __builtin_nontemporal_load((const vf4*)p);
    return make_float4(v.x, v.y, v.z, v.w);
}
__device__ __forceinline__ float2 ntload2(const float* p) {
    vf2 v = __builtin_nontemporal_load((const vf2*)p);
    return make_float2(v.x, v.y);
}

// ---------------------------------------------------------------------------
// Bucketization matching np.searchsorted(np.linspace(-1-eps, 1+eps, 9), x,
// 'right'). np.linspace is float64. (Verified: absmax 6e-5 in R1-R3.)
// ---------------------------------------------------------------------------
__device__ __forceinline__ int bucket1d(float xf) {
    const double start = -1.0 - 1e-6;
    const double stop  =  1.0 + 1e-6;
    const double step  = (stop - start) / 8.0;
    double x = (double)xf;
    int k = 0;
#pragma unroll
    for (int i = 0; i < 8; ++i) k += ((double)i * step + start <= x) ? 1 : 0;
    k += (stop <= x) ? 1 : 0;
    int b = k - 1;
    return b < 0 ? 0 : (b > 7 ? 7 : b);
}

// Kernel 1: zero sums8+out_part (contiguous 2.5 MB) + per-point bin +
// per-block histogram. 64 blocks x 256 threads.
__global__ __launch_bounds__(256) void k_bins(const float* __restrict__ coords,
                                              int* __restrict__ bins,
                                              int* __restrict__ hist_blk,
                                              float4* __restrict__ zero4) {
    __shared__ int s_h[HWBINS];
    const int tid = threadIdx.x;
    const int blk = blockIdx.x;
    {
        const float4 z = make_float4(0.f, 0.f, 0.f, 0.f);
        for (int i = blk * 256 + tid; i < ZERO_F4; i += 64 * 256)
            zero4[i] = z;
    }
    if (tid < HWBINS) s_h[tid] = 0;
    __syncthreads();
#pragma unroll
    for (int i = 0; i < 4; ++i) {
        int n = blk * 1024 + i * 256 + tid;
        float2 xy = *(const float2*)(coords + 2 * (size_t)n);
        int bx = bucket1d(xy.x);
        int by = bucket1d(xy.y);
        int bin = by * 8 + bx;   // (kx-1) + (ky-1)*H, H=8
        bins[n] = bin;
        atomicAdd(&s_h[bin], 1);
    }
    __syncthreads();
    if (tid < HWBINS) hist_blk[blk * HWBINS + tid] = s_h[tid];
}

// Kernel 2: one wave. counts[bin], exclusive bin offsets, per-block bases.
__global__ void k_scan(const int* __restrict__ hist_blk,
                       int* __restrict__ counts,
                       int* __restrict__ block_base) {
    const int b = threadIdx.x;   // 0..63
    int tot = 0;
#pragma unroll 8
    for (int blk = 0; blk < 64; ++blk) tot += hist_blk[blk * HWBINS + b];
    counts[b] = tot;
    int inc = tot;
#pragma unroll
    for (int d = 1; d < 64; d <<= 1) {
        int v = __shfl_up(inc, d, 64);
        if (b >= d) inc += v;
    }
    int run = inc - tot;   // exclusive offset of this bin
#pragma unroll 8
    for (int blk = 0; blk < 64; ++blk) {
        int h = hist_blk[blk * HWBINS + b];
        block_base[blk * HWBINS + b] = run;
        run += h;
    }
}

// Kernel 3: scatter (row, bin) pairs into bin-sorted order.
__global__ __launch_bounds__(256) void k_scatter(const int* __restrict__ bins,
                                                 const int* __restrict__ block_base,
                                                 int2* __restrict__ pairs) {
    __shared__ int s_cur[HWBINS];
    const int tid = threadIdx.x;
    const int blk = blockIdx.x;
    if (tid < HWBINS) s_cur[tid] = block_base[blk * HWBINS + tid];
    __syncthreads();
#pragma unroll
    for (int i = 0; i < 4; ++i) {
        int n = blk * 1024 + i * 256 + tid;
        int bin = bins[n];
        int pos = atomicAdd(&s_cur[bin], 1);
        pairs[pos] = make_int2(n, bin);
    }
}

// ---------------------------------------------------------------------------
// Kernel 4: the 256 MB pass. 1024 blocks (4/CU, 16 waves/CU). Wave = one
// batch, 64 lanes x float4 = all 256 ch of a row. Rows bin-sorted ->
// register accumulate; flush via global f32 atomics only at bin boundaries
// (~17K total), spread over 8 sum slots. 8-deep nontemporal prefetch:
// 8 KB/wave, 128 KB/CU in flight vs ~9 KB needed at 6.3 TB/s.
// ---------------------------------------------------------------------------
__global__ __launch_bounds__(256) void k_seg(const float* __restrict__ values,
                                             const int2* __restrict__ pairs,
                                             float* __restrict__ sums8) {
    __shared__ int2 sp[CHUNK];
    const int tid = threadIdx.x;
    const int r0  = blockIdx.x * CHUNK;
    if (tid < CHUNK) sp[tid] = pairs[r0 + tid];
    __syncthreads();

    const int w    = tid >> 6;    // batch
    const int lane = tid & 63;    // channel group (float4)
    const int slot = blockIdx.x & (SSLOTS - 1);
    const float* vb = values + (size_t)w * NPTS * CH + lane * 4;
    float* sb = sums8 + (size_t)slot * BATCH * KDIM + (size_t)w * KDIM + lane * 4;

    float4 acc = make_float4(0.f, 0.f, 0.f, 0.f);
    int cur = sp[0].y;

    auto flushfn = [&](int nb) {
        float* d = sb + (size_t)cur * CH;
        unsafeAtomicAdd(d + 0, acc.x);
        unsafeAtomicAdd(d + 1, acc.y);
        unsafeAtomicAdd(d + 2, acc.z);
        unsafeAtomicAdd(d + 3, acc.w);
        acc = make_float4(0.f, 0.f, 0.f, 0.f);
        cur = nb;
    };

    float4 a[8], nx[8];
#pragma unroll
    for (int j = 0; j < 8; ++j)
        a[j] = ntload4(vb + (size_t)sp[j].x * CH);

#pragma unroll
    for (int g = 0; g < CHUNK; g += 8) {
        if (g + 8 < CHUNK) {           // issue next group's loads first
#pragma unroll
            for (int j = 0; j < 8; ++j)
                nx[j] = ntload4(vb + (size_t)sp[g + 8 + j].x * CH);
        }
#pragma unroll
        for (int j = 0; j < 8; ++j) {
            int bj = sp[g + j].y;
            if (bj != cur) flushfn(bj);    // wave-uniform, rare
            acc.x += a[j].x; acc.y += a[j].y; acc.z += a[j].z; acc.w += a[j].w;
        }
        if (g + 8 < CHUNK) {
#pragma unroll
            for (int j = 0; j < 8; ++j) a[j] = nx[j];
        }
    }
    flushfn(cur);   // final flush
}

// ---------------------------------------------------------------------------
// Kernel 5: GEMM partials. 512 blocks (k-chunks of 32, 2/CU, 8 waves/CU),
// 256 thr, each thread owns a float2 of j for all 4 batches. Means (8-slot
// sum / count) computed into LDS. 32 fully-unrolled nontemporal W loads in
// flight. Partials into 64 slots (8-way atomic contention).
// ---------------------------------------------------------------------------
__global__ __launch_bounds__(256) void k_gemm_a(const float* __restrict__ Wm,
                                                const float* __restrict__ sums8,
                                                const int* __restrict__ counts,
                                                float* __restrict__ out_part) {
    __shared__ float s_m[4 * 32];   // [batch][kk]
    const int tid = threadIdx.x;
    const int kc  = blockIdx.x;     // 0..511
    const int k0  = kc * 32;
    if (tid < 128) {
        int bb = tid >> 5, kk = tid & 31, k = k0 + kk;
        float s = 0.f;
#pragma unroll
        for (int sl = 0; sl < SSLOTS; ++sl)
            s += sums8[(size_t)sl * BATCH * KDIM + (size_t)bb * KDIM + k];
        float cnt = (float)counts[k >> 8];
        s_m[tid] = s / fmaxf(cnt, 1.0f);
    }
    __syncthreads();

    const float* wp = Wm + (size_t)k0 * JDIM + 2 * tid;
    float2 a0 = {0.f, 0.f}, a1 = {0.f, 0.f}, a2 = {0.f, 0.f}, a3 = {0.f, 0.f};
#pragma unroll
    for (int kk = 0; kk < 32; ++kk) {
        float2 w = ntload2(wp + (size_t)kk * JDIM);
        float m0 = s_m[kk], m1 = s_m[32 + kk], m2 = s_m[64 + kk], m3 = s_m[96 + kk];
        a0.x += m0 * w.x; a0.y += m0 * w.y;
        a1.x += m1 * w.x; a1.y += m1 * w.y;
        a2.x += m2 * w.x; a2.y += m2 * w.y;
        a3.x += m3 * w.x; a3.y += m3 * w.y;
    }
    const int slot = kc & (GSLOTS - 1);
    float* op = out_part + (size_t)slot * 2048 + 2 * tid;
    unsafeAtomicAdd(op + 0,    a0.x); unsafeAtomicAdd(op + 1,    a0.y);
    unsafeAtomicAdd(op + 512,  a1.x); unsafeAtomicAdd(op + 513,  a1.y);
    unsafeAtomicAdd(op + 1024, a2.x); unsafeAtomicAdd(op + 1025, a2.y);
    unsafeAtomicAdd(op + 1536, a3.x); unsafeAtomicAdd(op + 1537, a3.y);
}

// Kernel 6: reduce 64 slots + bias -> out[4][512]. 512 KB read by 8 blocks.
__global__ __launch_bounds__(256) void k_gemm_b(const float* __restrict__ out_part,
                                                const float* __restrict__ bias,
                                                float* __restrict__ out) {
    const int idx = blockIdx.x * 256 + threadIdx.x;   // 0..2047
    const int j = idx & 511;
    float s = bias[j];
#pragma unroll
    for (int sl = 0; sl < GSLOTS; ++sl) s += out_part[(size_t)sl * 2048 + idx];
    out[idx] = s;
}

// ---------------------------------------------------------------------------
extern "C" void kernel_launch(void* const* d_in, const int* in_sizes, int n_in,
                              void* d_out, int out_size, void* d_ws, size_t ws_size,
                              hipStream_t stream) {
    const float* values = (const float*)d_in[0];  // [4, 65536, 256]
    const float* coords = (const float*)d_in[1];  // [65536, 2]
    const float* Wm     = (const float*)d_in[2];  // [16384, 512]
    const float* bias   = (const float*)d_in[3];  // [512]
    float* out = (float*)d_out;                   // [4, 512]

    char* ws = (char*)d_ws;
    // ws layout (bytes):
    int*   bins       = (int*)(ws + 0);            //  256 KB
    int*   hist_blk   = (int*)(ws + 262144);       //   16 KB
    int*   counts     = (int*)(ws + 278528);       //  256 B
    int*   block_base = (int*)(ws + 278784);       //   16 KB
    int2*  pairs      = (int2*)(ws + 295168);      //  512 KB
    float* sums8      = (float*)(ws + 819456);     //    2 MB  [8][4][16384]
    float* out_part   = (float*)(ws + 2916608);    //  512 KB  [64][2048] (MUST follow sums8: zeroed as one range)

    k_bins   <<<64, 256, 0, stream>>>(coords, bins, hist_blk, (float4*)sums8);
    k_scan   <<<1, 64, 0, stream>>>(hist_blk, counts, block_base);
    k_scatter<<<64, 256, 0, stream>>>(bins, block_base, pairs);
    k_seg    <<<NPTS / CHUNK, 256, 0, stream>>>(values, pairs, sums8);
    k_gemm_a <<<512, 256, 0, stream>>>(Wm, sums8, counts, out_part);
    k_gemm_b <<<8, 256, 0, stream>>>(out_part, bias, out);
}